// Round 10
// baseline (130.821 us; speedup 1.0000x reference)
//
#include <hip/hip_runtime.h>

// GCN N=100k, E=1.6M, H=64 — algebraic collapse + fixed-capacity bucket binning.
//
// Math (layer-1 input is [N,1], so each node's hidden state is a scalar function):
//   s[d] = dinv[d]*(sum_{src->d} dinv[src]*x[src] + dinv[d]*x[d])
//   relu(s*w1+b1) @ w2 = s*P^{sign(s)} + B^{sign(s)}   (P±,B± precomputed 64-vecs)
//   layer-2 scalars: a±[d], c±[d] (sign-split sums of dinv_s*s_s and dinv_s)
//   out[d] = relu(dinv[d]*(a+P+ + a-P- + c+B+ + c-B-) + b2) . wfc + bfc
//
// R10 (R8 base — R9's stagger/dual-histogram reverted, measured neutral):
//   k_place arrival-stash: pass 1 reads src+dst ONCE (int4) and stashes
//   packed value + bucket id in LDS (apv/alb); pass 2 is a pure LDS->LDS
//   bucket-sort (no global re-read — removes the cold-HBM src read that
//   stalled the sort phase). LDS 72->112KB; grid=196 < 256 CUs so still
//   1 block/CU — occupancy unaffected.
//
// Dispatches: memset -> k_place -> k_bdeg(+P in block0) -> k_bagg1 -> k_bagg2.

#define HCH 64
#define CHUNK 8192
#define BSH 7
#define BSZ 128          // nodes per bucket
#define NBMAX 1024

__device__ __forceinline__ void lds_addf(float* p, float v) {
    __hip_atomic_fetch_add(p, v, __ATOMIC_RELAXED, __HIP_MEMORY_SCOPE_WORKGROUP);
}

// bin edges into fixed bucket regions, bucket-sorted within the chunk so the
// global write-out is a coalesced linear sweep. cursorRel is ZERO-initialized;
// absolute base = bucket*cap + rel.
__global__ __launch_bounds__(512) void k_place(const int* __restrict__ src,
                                               const int* __restrict__ dst, int e,
                                               int nb, int cap,
                                               int* __restrict__ cursorRel,
                                               int* __restrict__ ov_cursor,
                                               int* __restrict__ packed,
                                               int2* __restrict__ ovbuf) {
    __shared__ int h[NBMAX];       // counts -> placement cursor
    __shared__ int scanE[NBMAX];   // chunk-local exclusive prefix
    __shared__ int basel[NBMAX];
    __shared__ int avail[NBMAX];
    __shared__ int apv[CHUNK];     // arrival-order packed values (pass-1 stash)
    __shared__ short alb[CHUNK];   // arrival-order bucket ids
    __shared__ int slpv[CHUNK];    // bucket-sorted packed values
    __shared__ short ssb[CHUNK];   // bucket id per sorted slot
    __shared__ int wsum[8];
    int t = threadIdx.x;
    for (int i = t; i < NBMAX; i += 512) h[i] = 0;
    __syncthreads();
    int cbase = blockIdx.x * CHUNK;
    int rem = min(e - cbase, CHUNK);

    // ---- pass 1: read src+dst ONCE, histogram + arrival stash ----
#pragma unroll
    for (int k = 0; k < CHUNK / 2048; k++) {
        int li = (k * 512 + t) * 4;
        if (li + 3 < rem) {
            int4 s4 = *(const int4*)(src + cbase + li);
            int4 d4 = *(const int4*)(dst + cbase + li);
#pragma unroll
            for (int q = 0; q < 4; q++) {
                int sv = (q == 0) ? s4.x : (q == 1) ? s4.y : (q == 2) ? s4.z : s4.w;
                int dv = (q == 0) ? d4.x : (q == 1) ? d4.y : (q == 2) ? d4.z : d4.w;
                int b = dv >> BSH;
                atomicAdd(&h[b], 1);
                apv[li + q] = sv | ((dv & (BSZ - 1)) << 17);
                alb[li + q] = (short)b;
            }
        } else {
            for (int q = li; q < rem && q < li + 4; q++) {
                int sv = src[cbase + q], dv = dst[cbase + q];
                int b = dv >> BSH;
                atomicAdd(&h[b], 1);
                apv[q] = sv | ((dv & (BSZ - 1)) << 17);
                alb[q] = (short)b;
            }
        }
    }
    __syncthreads();

    // ---- reservation (cursor-relative) + block scan over NBMAX entries ----
    int v0 = h[2 * t], v1 = h[2 * t + 1];
    for (int i = t; i < nb; i += 512) {
        int my = h[i];
        int av = 0, base = 0;
        if (my) {
            int baseRel = atomicAdd(&cursorRel[i], my);
            base = i * cap + baseRel;
            int room = cap - baseRel;
            av = room < 0 ? 0 : (room > my ? my : room);
        }
        basel[i] = base;
        avail[i] = av;
    }
    int lane = t & 63, wid = t >> 6;
    int s = v0 + v1;
    int incl = s;
#pragma unroll
    for (int d = 1; d < 64; d <<= 1) {
        int o = __shfl_up(incl, d, 64);
        if (lane >= d) incl += o;
    }
    if (lane == 63) wsum[wid] = incl;
    __syncthreads();                 // all h reads done; wsum level-1 written
    if (t < 8) {
        int v = wsum[t];
        int inc2 = v;
#pragma unroll
        for (int d = 1; d < 8; d <<= 1) {
            int o = __shfl_up(inc2, d, 8);
            if (t >= d) inc2 += o;
        }
        wsum[t] = inc2 - v;          // exclusive wave offset
    }
    for (int i = t; i < NBMAX; i += 512) h[i] = 0;  // reuse as placement cursor
    __syncthreads();
    int excl = incl - s + wsum[wid];
    scanE[2 * t] = excl;
    scanE[2 * t + 1] = excl + v0;
    __syncthreads();

    // ---- pass 2: pure LDS->LDS bucket sort from the arrival stash ----
#pragma unroll
    for (int k = 0; k < CHUNK / 2048; k++) {
        int li = (k * 512 + t) * 4;
        if (li + 3 < rem) {
            int4 a4 = *(const int4*)(&apv[li]);
#pragma unroll
            for (int q = 0; q < 4; q++) {
                int pv = (q == 0) ? a4.x : (q == 1) ? a4.y : (q == 2) ? a4.z : a4.w;
                int b = alb[li + q];
                int pos = scanE[b] + atomicAdd(&h[b], 1);
                slpv[pos] = pv;
                ssb[pos] = (short)b;
            }
        } else {
            for (int q = li; q < rem && q < li + 4; q++) {
                int pv = apv[q];
                int b = alb[q];
                int pos = scanE[b] + atomicAdd(&h[b], 1);
                slpv[pos] = pv;
                ssb[pos] = (short)b;
            }
        }
    }
    __syncthreads();

    // ---- pass 3: linear write-out (consecutive lanes -> consecutive addrs) ----
    for (int jj = t; jj < rem; jj += 512) {
        int b = ssb[jj];
        int loc = jj - scanE[b];
        int pv = slpv[jj];
        if (loc < avail[b]) {
            packed[basel[b] + loc] = pv;
        } else {
            int op = atomicAdd(ov_cursor, 1);
            ovbuf[op] = make_int2(pv & 0x1FFFF, (b << BSH) | (pv >> 17));
        }
    }
}

// per bucket: int histogram of local dst -> deg -> dinv, y = dinv*x.
// Block 0 additionally computes P[0..255]=P+,P-,B+,B- and P[256]=|B| flag
// (overlapped with the other 781 blocks' bucket work).
__global__ __launch_bounds__(512) void k_bdeg(const int* __restrict__ packed,
                                              const int* __restrict__ cursorRel,
                                              const int* __restrict__ ov_cursor,
                                              const int2* __restrict__ ovbuf,
                                              int cap, const float* __restrict__ x, int n,
                                              const float* __restrict__ w1,
                                              const float* __restrict__ b1,
                                              const float* __restrict__ w2,
                                              float* __restrict__ P,
                                              float* __restrict__ dinv,
                                              float* __restrict__ y) {
    __shared__ int cnt[BSZ];
    __shared__ float part[8][4][HCH];
    __shared__ float fsum;
    int bk = blockIdx.x, t = threadIdx.x;

    if (bk == 0) {
        // ---- P±/B± precompute (same math as the old k_init) ----
        if (t == 0) fsum = 0.f;
        int j = t & 63, seg = t >> 6;
        float pp = 0.f, pm = 0.f, bp = 0.f, bm = 0.f;
#pragma unroll
        for (int kk = 0; kk < 8; kk++) {
            int k = seg * 8 + kk;
            float w = w1[k], b = b1[k], v = w2[k * HCH + j];
            if (w > 0.f) { pp += w * v; bp += b * v; }
            else if (w < 0.f) { pm += w * v; bm += b * v; }
            else { float rb = b > 0.f ? b : 0.f; bp += rb * v; bm += rb * v; }
        }
        part[seg][0][j] = pp; part[seg][1][j] = pm;
        part[seg][2][j] = bp; part[seg][3][j] = bm;
        __syncthreads();
        if (t < 4 * HCH) {
            int c = t >> 6, jj = t & 63;
            float ssum = 0.f;
#pragma unroll
            for (int g = 0; g < 8; g++) ssum += part[g][c][jj];
            P[t] = ssum;
            if (c >= 2) lds_addf(&fsum, fabsf(ssum));
        }
        __syncthreads();
        if (t == 0) P[4 * HCH] = fsum;
    }

    int bbase = bk * cap;
    int bcnt = min(cursorRel[bk], cap);
    if (t < BSZ) cnt[t] = 0;
    __syncthreads();
    for (int base = 0; base < bcnt; base += 2048) {
        int i0 = base + t * 4;
        if (i0 + 3 < bcnt) {
            int4 p = *(const int4*)(packed + bbase + i0);
            atomicAdd(&cnt[p.x >> 17], 1);
            atomicAdd(&cnt[p.y >> 17], 1);
            atomicAdd(&cnt[p.z >> 17], 1);
            atomicAdd(&cnt[p.w >> 17], 1);
        } else {
            for (int i = i0; i < bcnt && i < i0 + 4; i++)
                atomicAdd(&cnt[packed[bbase + i] >> 17], 1);
        }
    }
    int ovc = *ov_cursor;
    for (int i = t; i < ovc; i += 512) {
        int2 o = ovbuf[i];
        if ((o.y >> BSH) == bk) atomicAdd(&cnt[o.y & (BSZ - 1)], 1);
    }
    __syncthreads();
    int node = (bk << BSH) + t;
    if (t < BSZ && node < n) {
        float dv = rsqrtf((float)(cnt[t] + 1));  // +1 self-loop
        dinv[node] = dv;
        y[node] = dv * x[node];
    }
}

// per bucket: acc[localdst] += y[src] -> s -> val = dinv*s
__global__ __launch_bounds__(512) void k_bagg1(const int* __restrict__ packed,
                                               const int* __restrict__ cursorRel,
                                               const int* __restrict__ ov_cursor,
                                               const int2* __restrict__ ovbuf,
                                               int cap,
                                               const float* __restrict__ dinv,
                                               const float* __restrict__ y, int n,
                                               float* __restrict__ val) {
    __shared__ float acc[BSZ];
    int bk = blockIdx.x, t = threadIdx.x;
    int bbase = bk * cap;
    int bcnt = min(cursorRel[bk], cap);
    if (t < BSZ) acc[t] = 0.f;
    __syncthreads();
    for (int base = 0; base < bcnt; base += 2048) {
        int i0 = base + t * 4;
        if (i0 + 3 < bcnt) {
            int4 p = *(const int4*)(packed + bbase + i0);
            float y0 = y[p.x & 0x1FFFF], y1 = y[p.y & 0x1FFFF];
            float y2 = y[p.z & 0x1FFFF], y3 = y[p.w & 0x1FFFF];
            lds_addf(&acc[p.x >> 17], y0);
            lds_addf(&acc[p.y >> 17], y1);
            lds_addf(&acc[p.z >> 17], y2);
            lds_addf(&acc[p.w >> 17], y3);
        } else {
            for (int i = i0; i < bcnt && i < i0 + 4; i++) {
                int p = packed[bbase + i];
                lds_addf(&acc[p >> 17], y[p & 0x1FFFF]);
            }
        }
    }
    int ovc = *ov_cursor;
    for (int i = t; i < ovc; i += 512) {
        int2 o = ovbuf[i];
        if ((o.y >> BSH) == bk) lds_addf(&acc[o.y & (BSZ - 1)], y[o.x]);
    }
    __syncthreads();
    int node = (bk << BSH) + t;
    if (t < BSZ && node < n) {
        float dv = dinv[node];
        float s = dv * (acc[t] + y[node]);  // y[node] = dv*x[node]
        val[node] = dv * s;
    }
}

// per bucket: sign-split accumulate of val[src] + fused epilogue -> out
__global__ __launch_bounds__(512) void k_bagg2(const int* __restrict__ packed,
                                               const int* __restrict__ cursorRel,
                                               const int* __restrict__ ov_cursor,
                                               const int2* __restrict__ ovbuf,
                                               int cap, const float* __restrict__ val,
                                               const float* __restrict__ dinv,
                                               const float* __restrict__ P,
                                               const float* __restrict__ b2,
                                               const float* __restrict__ wfc,
                                               const float* __restrict__ bfc,
                                               float* __restrict__ out, int n) {
    __shared__ float aa[2 * BSZ];   // [0..BSZ): positive, [BSZ..2BSZ): negative
    __shared__ float cc[2 * BSZ];
    __shared__ float sP[4 * HCH], sb2[HCH], swfc[HCH];
    __shared__ float sflag;
    int bk = blockIdx.x, t = threadIdx.x;
    int bbase = bk * cap;
    int bcnt = min(cursorRel[bk], cap);
    if (t < 2 * BSZ) { aa[t] = 0.f; cc[t] = 0.f; }
    if (t < 4 * HCH) sP[t] = P[t];
    if (t >= 256 && t < 320) sb2[t - 256] = b2[t - 256];
    if (t >= 320 && t < 384) swfc[t - 320] = wfc[t - 320];
    if (t == 448) sflag = P[4 * HCH];
    __syncthreads();
    bool useB = sflag != 0.f;
    for (int base = 0; base < bcnt; base += 2048) {
        int i0 = base + t * 4;
        if (i0 + 3 < bcnt) {
            int4 p = *(const int4*)(packed + bbase + i0);
            float v0 = val[p.x & 0x1FFFF], v1 = val[p.y & 0x1FFFF];
            float v2 = val[p.z & 0x1FFFF], v3 = val[p.w & 0x1FFFF];
            int o0 = (v0 > 0.f ? 0 : BSZ) + (p.x >> 17);
            int o1 = (v1 > 0.f ? 0 : BSZ) + (p.y >> 17);
            int o2 = (v2 > 0.f ? 0 : BSZ) + (p.z >> 17);
            int o3 = (v3 > 0.f ? 0 : BSZ) + (p.w >> 17);
            lds_addf(&aa[o0], v0); lds_addf(&aa[o1], v1);
            lds_addf(&aa[o2], v2); lds_addf(&aa[o3], v3);
            if (useB) {
                lds_addf(&cc[o0], dinv[p.x & 0x1FFFF]);
                lds_addf(&cc[o1], dinv[p.y & 0x1FFFF]);
                lds_addf(&cc[o2], dinv[p.z & 0x1FFFF]);
                lds_addf(&cc[o3], dinv[p.w & 0x1FFFF]);
            }
        } else {
            for (int i = i0; i < bcnt && i < i0 + 4; i++) {
                int p = packed[bbase + i];
                float v = val[p & 0x1FFFF];
                int off = (v > 0.f ? 0 : BSZ) + (p >> 17);
                lds_addf(&aa[off], v);
                if (useB) lds_addf(&cc[off], dinv[p & 0x1FFFF]);
            }
        }
    }
    int ovc = *ov_cursor;
    for (int i = t; i < ovc; i += 512) {
        int2 o = ovbuf[i];
        if ((o.y >> BSH) == bk) {
            float v = val[o.x];
            int off = (v > 0.f ? 0 : BSZ) + (o.y & (BSZ - 1));
            lds_addf(&aa[off], v);
            if (useB) lds_addf(&cc[off], dinv[o.x]);
        }
    }
    __syncthreads();
    int node = (bk << BSH) + t;
    if (t >= BSZ || node >= n) return;
    float a_p = aa[t], a_m = aa[BSZ + t], c_p = cc[t], c_m = cc[BSZ + t];
    float dv = dinv[node];
    float sx = val[node];  // self-loop
    if (sx > 0.f) { a_p += sx; c_p += dv; }
    else          { a_m += sx; c_m += dv; }
    float acc = 0.f;
#pragma unroll 8
    for (int j = 0; j < HCH; j++) {
        float z = dv * (a_p * sP[j] + a_m * sP[HCH + j] +
                        c_p * sP[2 * HCH + j] + c_m * sP[3 * HCH + j]) + sb2[j];
        z = z > 0.f ? z : 0.f;
        acc += z * swfc[j];
    }
    out[node] = acc + bfc[0];
}

extern "C" void kernel_launch(void* const* d_in, const int* in_sizes, int n_in,
                              void* d_out, int out_size, void* d_ws, size_t ws_size,
                              hipStream_t stream) {
    const float* x   = (const float*)d_in[0];
    const int*   ei  = (const int*)d_in[1];
    const float* w1  = (const float*)d_in[2];
    const float* b1  = (const float*)d_in[3];
    const float* w2  = (const float*)d_in[4];
    const float* b2  = (const float*)d_in[5];
    const float* wfc = (const float*)d_in[6];
    const float* bfc = (const float*)d_in[7];
    float* out = (float*)d_out;

    const int n = in_sizes[0];      // 100000
    const int e = in_sizes[1] / 2;  // 1600000
    const int* src = ei;
    const int* dst = ei + e;

    const int nb = (n + BSZ - 1) >> BSH;          // 782 buckets
    int avg = (e + nb - 1) / nb;                  // ~2047
    int cap = ((avg + avg / 4 + 64) + 15) & ~15;  // ~13 sigma headroom, 16-aligned

    auto al = [](size_t v) { return (v + 255) & ~(size_t)255; };
    char* ws = (char*)d_ws;
    size_t o = 0;
    int* cursorRel = (int*)(ws + o);  o = al(o + (size_t)NBMAX * 4);   // ws+0
    int* ov_cursor = (int*)(ws + o);  o = al(o + 256);                 // ws+4096
    float* dinv  = (float*)(ws + o);  o = al(o + (size_t)n * 4);
    float* y     = (float*)(ws + o);  o = al(o + (size_t)n * 4);
    float* val   = (float*)(ws + o);  o = al(o + (size_t)n * 4);
    float* P     = (float*)(ws + o);  o = al(o + (4 * HCH + 8) * 4);
    int* packed  = (int*)(ws + o);    o = al(o + (size_t)nb * cap * 4);
    int2* ovbuf  = (int2*)(ws + o);   o = al(o + (size_t)e * 8);
    (void)ws_size;

    const int nchunk = (e + CHUNK - 1) / CHUNK;  // 196 chunks

    // zero cursorRel[NBMAX] + ov_cursor (contiguous from ws+0)
    hipMemsetAsync(ws, 0, (size_t)NBMAX * 4 + 4, stream);
    k_place<<<nchunk, 512, 0, stream>>>(src, dst, e, nb, cap, cursorRel, ov_cursor,
                                        packed, ovbuf);
    k_bdeg<<<nb, 512, 0, stream>>>(packed, cursorRel, ov_cursor, ovbuf, cap, x, n,
                                   w1, b1, w2, P, dinv, y);
    k_bagg1<<<nb, 512, 0, stream>>>(packed, cursorRel, ov_cursor, ovbuf, cap, dinv, y,
                                    n, val);
    k_bagg2<<<nb, 512, 0, stream>>>(packed, cursorRel, ov_cursor, ovbuf, cap, val,
                                    dinv, P, b2, wfc, bfc, out, n);
}

// Round 11
// 128.427 us; speedup vs baseline: 1.0186x; 1.0186x over previous
//
#include <hip/hip_runtime.h>

// GCN N=100k, E=1.6M, H=64 — algebraic collapse + fixed-capacity bucket binning.
//
// Math (layer-1 input is [N,1], so each node's hidden state is a scalar function):
//   s[d] = dinv[d]*(sum_{src->d} dinv[src]*x[src] + dinv[d]*x[d])
//   relu(s*w1+b1) @ w2 = s*P^{sign(s)} + B^{sign(s)}   (P±,B± precomputed 64-vecs)
//   layer-2 scalars: a±[d], c±[d] (sign-split sums of dinv_s*s_s and dinv_s)
//   out[d] = relu(dinv[d]*(a+P+ + a-P- + c+B+ + c-B-) + b2) . wfc + bfc
//
// R11 = R8 EXACT restored (best measured: 128.9us). R9 (contention smoothing)
// and R10 (arrival-stash) both measured neutral/negative and are reverted.
// Structure: two-pass sorted k_place at CHUNK=8192 with relative cursors
// (4KB memset init), P±/B± precompute overlapped in block 0 of k_bdeg,
// val as scalar float, fused epilogue in k_bagg2.
//
// Dispatches: memset -> k_place -> k_bdeg(+P in block0) -> k_bagg1 -> k_bagg2.

#define HCH 64
#define CHUNK 8192
#define BSH 7
#define BSZ 128          // nodes per bucket
#define NBMAX 1024

__device__ __forceinline__ void lds_addf(float* p, float v) {
    __hip_atomic_fetch_add(p, v, __ATOMIC_RELAXED, __HIP_MEMORY_SCOPE_WORKGROUP);
}

// bin edges into fixed bucket regions, bucket-sorted within the chunk so the
// global write-out is a coalesced linear sweep. cursorRel is ZERO-initialized;
// absolute base = bucket*cap + rel.
__global__ __launch_bounds__(512) void k_place(const int* __restrict__ src,
                                               const int* __restrict__ dst, int e,
                                               int nb, int cap,
                                               int* __restrict__ cursorRel,
                                               int* __restrict__ ov_cursor,
                                               int* __restrict__ packed,
                                               int2* __restrict__ ovbuf) {
    __shared__ int h[NBMAX];       // counts -> placement cursor
    __shared__ int scanE[NBMAX];   // chunk-local exclusive prefix
    __shared__ int basel[NBMAX];
    __shared__ int avail[NBMAX];
    __shared__ int slpv[CHUNK];    // bucket-sorted packed values
    __shared__ short ssb[CHUNK];   // bucket id per sorted slot
    __shared__ int wsum[8];
    int t = threadIdx.x;
    for (int i = t; i < NBMAX; i += 512) h[i] = 0;
    __syncthreads();
    int cbase = blockIdx.x * CHUNK;
    int rem = min(e - cbase, CHUNK);

    // ---- pass 1: histogram (dst only) ----
#pragma unroll
    for (int k = 0; k < CHUNK / 2048; k++) {
        int li = (k * 512 + t) * 4;
        if (li + 3 < rem) {
            int4 d4 = *(const int4*)(dst + cbase + li);
            atomicAdd(&h[d4.x >> BSH], 1);
            atomicAdd(&h[d4.y >> BSH], 1);
            atomicAdd(&h[d4.z >> BSH], 1);
            atomicAdd(&h[d4.w >> BSH], 1);
        } else {
            for (int q = li; q < rem && q < li + 4; q++)
                atomicAdd(&h[dst[cbase + q] >> BSH], 1);
        }
    }
    __syncthreads();

    // ---- reservation (cursor-relative) + block scan over NBMAX entries ----
    int v0 = h[2 * t], v1 = h[2 * t + 1];
    for (int i = t; i < nb; i += 512) {
        int my = h[i];
        int av = 0, base = 0;
        if (my) {
            int baseRel = atomicAdd(&cursorRel[i], my);
            base = i * cap + baseRel;
            int room = cap - baseRel;
            av = room < 0 ? 0 : (room > my ? my : room);
        }
        basel[i] = base;
        avail[i] = av;
    }
    int lane = t & 63, wid = t >> 6;
    int s = v0 + v1;
    int incl = s;
#pragma unroll
    for (int d = 1; d < 64; d <<= 1) {
        int o = __shfl_up(incl, d, 64);
        if (lane >= d) incl += o;
    }
    if (lane == 63) wsum[wid] = incl;
    __syncthreads();                 // all h reads done; wsum level-1 written
    if (t < 8) {
        int v = wsum[t];
        int inc2 = v;
#pragma unroll
        for (int d = 1; d < 8; d <<= 1) {
            int o = __shfl_up(inc2, d, 8);
            if (t >= d) inc2 += o;
        }
        wsum[t] = inc2 - v;          // exclusive wave offset
    }
    for (int i = t; i < NBMAX; i += 512) h[i] = 0;  // reuse as placement cursor
    __syncthreads();
    int excl = incl - s + wsum[wid];
    scanE[2 * t] = excl;
    scanE[2 * t + 1] = excl + v0;
    __syncthreads();

    // ---- pass 2: re-read edges (L2-hot), place bucket-sorted into LDS ----
#pragma unroll
    for (int k = 0; k < CHUNK / 2048; k++) {
        int li = (k * 512 + t) * 4;
        if (li + 3 < rem) {
            int4 s4 = *(const int4*)(src + cbase + li);
            int4 d4 = *(const int4*)(dst + cbase + li);
#pragma unroll
            for (int q = 0; q < 4; q++) {
                int sv = (q == 0) ? s4.x : (q == 1) ? s4.y : (q == 2) ? s4.z : s4.w;
                int dv = (q == 0) ? d4.x : (q == 1) ? d4.y : (q == 2) ? d4.z : d4.w;
                int b = dv >> BSH;
                int pos = scanE[b] + atomicAdd(&h[b], 1);
                slpv[pos] = sv | ((dv & (BSZ - 1)) << 17);
                ssb[pos] = (short)b;
            }
        } else {
            for (int q = li; q < rem && q < li + 4; q++) {
                int sv = src[cbase + q], dv = dst[cbase + q];
                int b = dv >> BSH;
                int pos = scanE[b] + atomicAdd(&h[b], 1);
                slpv[pos] = sv | ((dv & (BSZ - 1)) << 17);
                ssb[pos] = (short)b;
            }
        }
    }
    __syncthreads();

    // ---- pass 3: linear write-out (consecutive lanes -> consecutive addrs) ----
    for (int jj = t; jj < rem; jj += 512) {
        int b = ssb[jj];
        int loc = jj - scanE[b];
        int pv = slpv[jj];
        if (loc < avail[b]) {
            packed[basel[b] + loc] = pv;
        } else {
            int op = atomicAdd(ov_cursor, 1);
            ovbuf[op] = make_int2(pv & 0x1FFFF, (b << BSH) | (pv >> 17));
        }
    }
}

// per bucket: int histogram of local dst -> deg -> dinv, y = dinv*x.
// Block 0 additionally computes P[0..255]=P+,P-,B+,B- and P[256]=|B| flag
// (overlapped with the other 781 blocks' bucket work).
__global__ __launch_bounds__(512) void k_bdeg(const int* __restrict__ packed,
                                              const int* __restrict__ cursorRel,
                                              const int* __restrict__ ov_cursor,
                                              const int2* __restrict__ ovbuf,
                                              int cap, const float* __restrict__ x, int n,
                                              const float* __restrict__ w1,
                                              const float* __restrict__ b1,
                                              const float* __restrict__ w2,
                                              float* __restrict__ P,
                                              float* __restrict__ dinv,
                                              float* __restrict__ y) {
    __shared__ int cnt[BSZ];
    __shared__ float part[8][4][HCH];
    __shared__ float fsum;
    int bk = blockIdx.x, t = threadIdx.x;

    if (bk == 0) {
        // ---- P±/B± precompute (same math as the old k_init) ----
        if (t == 0) fsum = 0.f;
        int j = t & 63, seg = t >> 6;
        float pp = 0.f, pm = 0.f, bp = 0.f, bm = 0.f;
#pragma unroll
        for (int kk = 0; kk < 8; kk++) {
            int k = seg * 8 + kk;
            float w = w1[k], b = b1[k], v = w2[k * HCH + j];
            if (w > 0.f) { pp += w * v; bp += b * v; }
            else if (w < 0.f) { pm += w * v; bm += b * v; }
            else { float rb = b > 0.f ? b : 0.f; bp += rb * v; bm += rb * v; }
        }
        part[seg][0][j] = pp; part[seg][1][j] = pm;
        part[seg][2][j] = bp; part[seg][3][j] = bm;
        __syncthreads();
        if (t < 4 * HCH) {
            int c = t >> 6, jj = t & 63;
            float ssum = 0.f;
#pragma unroll
            for (int g = 0; g < 8; g++) ssum += part[g][c][jj];
            P[t] = ssum;
            if (c >= 2) lds_addf(&fsum, fabsf(ssum));
        }
        __syncthreads();
        if (t == 0) P[4 * HCH] = fsum;
    }

    int bbase = bk * cap;
    int bcnt = min(cursorRel[bk], cap);
    if (t < BSZ) cnt[t] = 0;
    __syncthreads();
    for (int base = 0; base < bcnt; base += 2048) {
        int i0 = base + t * 4;
        if (i0 + 3 < bcnt) {
            int4 p = *(const int4*)(packed + bbase + i0);
            atomicAdd(&cnt[p.x >> 17], 1);
            atomicAdd(&cnt[p.y >> 17], 1);
            atomicAdd(&cnt[p.z >> 17], 1);
            atomicAdd(&cnt[p.w >> 17], 1);
        } else {
            for (int i = i0; i < bcnt && i < i0 + 4; i++)
                atomicAdd(&cnt[packed[bbase + i] >> 17], 1);
        }
    }
    int ovc = *ov_cursor;
    for (int i = t; i < ovc; i += 512) {
        int2 o = ovbuf[i];
        if ((o.y >> BSH) == bk) atomicAdd(&cnt[o.y & (BSZ - 1)], 1);
    }
    __syncthreads();
    int node = (bk << BSH) + t;
    if (t < BSZ && node < n) {
        float dv = rsqrtf((float)(cnt[t] + 1));  // +1 self-loop
        dinv[node] = dv;
        y[node] = dv * x[node];
    }
}

// per bucket: acc[localdst] += y[src] -> s -> val = dinv*s
__global__ __launch_bounds__(512) void k_bagg1(const int* __restrict__ packed,
                                               const int* __restrict__ cursorRel,
                                               const int* __restrict__ ov_cursor,
                                               const int2* __restrict__ ovbuf,
                                               int cap,
                                               const float* __restrict__ dinv,
                                               const float* __restrict__ y, int n,
                                               float* __restrict__ val) {
    __shared__ float acc[BSZ];
    int bk = blockIdx.x, t = threadIdx.x;
    int bbase = bk * cap;
    int bcnt = min(cursorRel[bk], cap);
    if (t < BSZ) acc[t] = 0.f;
    __syncthreads();
    for (int base = 0; base < bcnt; base += 2048) {
        int i0 = base + t * 4;
        if (i0 + 3 < bcnt) {
            int4 p = *(const int4*)(packed + bbase + i0);
            float y0 = y[p.x & 0x1FFFF], y1 = y[p.y & 0x1FFFF];
            float y2 = y[p.z & 0x1FFFF], y3 = y[p.w & 0x1FFFF];
            lds_addf(&acc[p.x >> 17], y0);
            lds_addf(&acc[p.y >> 17], y1);
            lds_addf(&acc[p.z >> 17], y2);
            lds_addf(&acc[p.w >> 17], y3);
        } else {
            for (int i = i0; i < bcnt && i < i0 + 4; i++) {
                int p = packed[bbase + i];
                lds_addf(&acc[p >> 17], y[p & 0x1FFFF]);
            }
        }
    }
    int ovc = *ov_cursor;
    for (int i = t; i < ovc; i += 512) {
        int2 o = ovbuf[i];
        if ((o.y >> BSH) == bk) lds_addf(&acc[o.y & (BSZ - 1)], y[o.x]);
    }
    __syncthreads();
    int node = (bk << BSH) + t;
    if (t < BSZ && node < n) {
        float dv = dinv[node];
        float s = dv * (acc[t] + y[node]);  // y[node] = dv*x[node]
        val[node] = dv * s;
    }
}

// per bucket: sign-split accumulate of val[src] + fused epilogue -> out
__global__ __launch_bounds__(512) void k_bagg2(const int* __restrict__ packed,
                                               const int* __restrict__ cursorRel,
                                               const int* __restrict__ ov_cursor,
                                               const int2* __restrict__ ovbuf,
                                               int cap, const float* __restrict__ val,
                                               const float* __restrict__ dinv,
                                               const float* __restrict__ P,
                                               const float* __restrict__ b2,
                                               const float* __restrict__ wfc,
                                               const float* __restrict__ bfc,
                                               float* __restrict__ out, int n) {
    __shared__ float aa[2 * BSZ];   // [0..BSZ): positive, [BSZ..2BSZ): negative
    __shared__ float cc[2 * BSZ];
    __shared__ float sP[4 * HCH], sb2[HCH], swfc[HCH];
    __shared__ float sflag;
    int bk = blockIdx.x, t = threadIdx.x;
    int bbase = bk * cap;
    int bcnt = min(cursorRel[bk], cap);
    if (t < 2 * BSZ) { aa[t] = 0.f; cc[t] = 0.f; }
    if (t < 4 * HCH) sP[t] = P[t];
    if (t >= 256 && t < 320) sb2[t - 256] = b2[t - 256];
    if (t >= 320 && t < 384) swfc[t - 320] = wfc[t - 320];
    if (t == 448) sflag = P[4 * HCH];
    __syncthreads();
    bool useB = sflag != 0.f;
    for (int base = 0; base < bcnt; base += 2048) {
        int i0 = base + t * 4;
        if (i0 + 3 < bcnt) {
            int4 p = *(const int4*)(packed + bbase + i0);
            float v0 = val[p.x & 0x1FFFF], v1 = val[p.y & 0x1FFFF];
            float v2 = val[p.z & 0x1FFFF], v3 = val[p.w & 0x1FFFF];
            int o0 = (v0 > 0.f ? 0 : BSZ) + (p.x >> 17);
            int o1 = (v1 > 0.f ? 0 : BSZ) + (p.y >> 17);
            int o2 = (v2 > 0.f ? 0 : BSZ) + (p.z >> 17);
            int o3 = (v3 > 0.f ? 0 : BSZ) + (p.w >> 17);
            lds_addf(&aa[o0], v0); lds_addf(&aa[o1], v1);
            lds_addf(&aa[o2], v2); lds_addf(&aa[o3], v3);
            if (useB) {
                lds_addf(&cc[o0], dinv[p.x & 0x1FFFF]);
                lds_addf(&cc[o1], dinv[p.y & 0x1FFFF]);
                lds_addf(&cc[o2], dinv[p.z & 0x1FFFF]);
                lds_addf(&cc[o3], dinv[p.w & 0x1FFFF]);
            }
        } else {
            for (int i = i0; i < bcnt && i < i0 + 4; i++) {
                int p = packed[bbase + i];
                float v = val[p & 0x1FFFF];
                int off = (v > 0.f ? 0 : BSZ) + (p >> 17);
                lds_addf(&aa[off], v);
                if (useB) lds_addf(&cc[off], dinv[p & 0x1FFFF]);
            }
        }
    }
    int ovc = *ov_cursor;
    for (int i = t; i < ovc; i += 512) {
        int2 o = ovbuf[i];
        if ((o.y >> BSH) == bk) {
            float v = val[o.x];
            int off = (v > 0.f ? 0 : BSZ) + (o.y & (BSZ - 1));
            lds_addf(&aa[off], v);
            if (useB) lds_addf(&cc[off], dinv[o.x]);
        }
    }
    __syncthreads();
    int node = (bk << BSH) + t;
    if (t >= BSZ || node >= n) return;
    float a_p = aa[t], a_m = aa[BSZ + t], c_p = cc[t], c_m = cc[BSZ + t];
    float dv = dinv[node];
    float sx = val[node];  // self-loop
    if (sx > 0.f) { a_p += sx; c_p += dv; }
    else          { a_m += sx; c_m += dv; }
    float acc = 0.f;
#pragma unroll 8
    for (int j = 0; j < HCH; j++) {
        float z = dv * (a_p * sP[j] + a_m * sP[HCH + j] +
                        c_p * sP[2 * HCH + j] + c_m * sP[3 * HCH + j]) + sb2[j];
        z = z > 0.f ? z : 0.f;
        acc += z * swfc[j];
    }
    out[node] = acc + bfc[0];
}

extern "C" void kernel_launch(void* const* d_in, const int* in_sizes, int n_in,
                              void* d_out, int out_size, void* d_ws, size_t ws_size,
                              hipStream_t stream) {
    const float* x   = (const float*)d_in[0];
    const int*   ei  = (const int*)d_in[1];
    const float* w1  = (const float*)d_in[2];
    const float* b1  = (const float*)d_in[3];
    const float* w2  = (const float*)d_in[4];
    const float* b2  = (const float*)d_in[5];
    const float* wfc = (const float*)d_in[6];
    const float* bfc = (const float*)d_in[7];
    float* out = (float*)d_out;

    const int n = in_sizes[0];      // 100000
    const int e = in_sizes[1] / 2;  // 1600000
    const int* src = ei;
    const int* dst = ei + e;

    const int nb = (n + BSZ - 1) >> BSH;          // 782 buckets
    int avg = (e + nb - 1) / nb;                  // ~2047
    int cap = ((avg + avg / 4 + 64) + 15) & ~15;  // ~13 sigma headroom, 16-aligned

    auto al = [](size_t v) { return (v + 255) & ~(size_t)255; };
    char* ws = (char*)d_ws;
    size_t o = 0;
    int* cursorRel = (int*)(ws + o);  o = al(o + (size_t)NBMAX * 4);   // ws+0
    int* ov_cursor = (int*)(ws + o);  o = al(o + 256);                 // ws+4096
    float* dinv  = (float*)(ws + o);  o = al(o + (size_t)n * 4);
    float* y     = (float*)(ws + o);  o = al(o + (size_t)n * 4);
    float* val   = (float*)(ws + o);  o = al(o + (size_t)n * 4);
    float* P     = (float*)(ws + o);  o = al(o + (4 * HCH + 8) * 4);
    int* packed  = (int*)(ws + o);    o = al(o + (size_t)nb * cap * 4);
    int2* ovbuf  = (int2*)(ws + o);   o = al(o + (size_t)e * 8);
    (void)ws_size;

    const int nchunk = (e + CHUNK - 1) / CHUNK;  // 196 chunks

    // zero cursorRel[NBMAX] + ov_cursor (contiguous from ws+0)
    hipMemsetAsync(ws, 0, (size_t)NBMAX * 4 + 4, stream);
    k_place<<<nchunk, 512, 0, stream>>>(src, dst, e, nb, cap, cursorRel, ov_cursor,
                                        packed, ovbuf);
    k_bdeg<<<nb, 512, 0, stream>>>(packed, cursorRel, ov_cursor, ovbuf, cap, x, n,
                                   w1, b1, w2, P, dinv, y);
    k_bagg1<<<nb, 512, 0, stream>>>(packed, cursorRel, ov_cursor, ovbuf, cap, dinv, y,
                                    n, val);
    k_bagg2<<<nb, 512, 0, stream>>>(packed, cursorRel, ov_cursor, ovbuf, cap, val,
                                    dinv, P, b2, wfc, bfc, out, n);
}